// Round 5
// baseline (183.404 us; speedup 1.0000x reference)
//
#include <hip/hip_runtime.h>

// Per-batch segment_sum with SORTED segment ids.
//   embeddings: (B=64, S=512, D=768) fp32; segment_ids: (B,S) int32 sorted.
//   out = concat(agg[:,0] (B,D), agg[:,1:] (B,S-1,D)) — flat B*S*D floats.
//
// R6 post-mortem: nt stores perfectly null (FETCH 49.67 MB unchanged).
// Falsified so far: wave structure (x3), cache policy (x1) — all ~62 us.
// Datum: fillBufferAligned moves 393 MB @ 6.54 TB/s on this device while we
// achieve 3.2 TB/s effective on 201 MB obligatory traffic (floor ~32 us).
// Last theory standing: STREAM SHAPE. We issue thousands of short id-gated
// bursts completing in scrambled order, and R5's batch loop drained vmcnt(0)
// before every consume phase (zero reads in flight half the time). The fill
// kernel's streams are long, affine, sequential.
//
// R7: copy-like restructure of the R5 value-window scan:
//   1. DOUBLE-BUFFERED batch pipeline: issue batch k+1's 8 affine row loads
//      BEFORE consuming batch k — one 24 KB batch always in flight per block.
//      All register arrays statically indexed (no scratch).
//   2. XCD-chunked bijective block swizzle (2048 %% 8 == 0): each XCD owns
//      contiguous value-windows -> sequential per-XCD read+write streams.
//   3. 2048 blocks = 8/CU, 16 segment values per block; flush logic identical
//      to the verified R5 scan (absmax 0.0): boundaries from 17 ballot
//      prefix-counts, ascending row order, empty segments emit zero rows.
// Prediction: dur 62 -> 40-50 us if stream shape is the lever; if ~62 again,
// every lever is falsified and this is the platform ceiling for this op.

constexpr int B  = 64;
constexpr int S  = 512;
constexpr int D  = 768;
constexpr int D4 = D / 4;            // 192 float4 per row
constexpr int VALS    = 16;          // segment values per block
constexpr int THREADS = 192;         // 3 waves; thread t owns float4 column t
constexpr int WPB     = S / VALS;    // 32 value-windows per batch
constexpr int NBLK    = B * WPB;     // 2048 blocks = 8 per CU
constexpr int BATCH   = 8;           // rows per load batch (24 KB/block)

__device__ __forceinline__ void facc(float4& a, const float4& e) {
  a.x += e.x; a.y += e.y; a.z += e.z; a.w += e.w;
}

__device__ __forceinline__ float4* out_row(float4* out, int b, int g) {
  return (g == 0) ? out + (size_t)b * D4
                  : out + (size_t)B * D4 + ((size_t)b * (S - 1) + (g - 1)) * D4;
}

__global__ __launch_bounds__(THREADS) void segsum_pipe_kernel(
    const float4* __restrict__ emb,   // (B*S*D4)
    const int*    __restrict__ seg,   // (B*S)
    float4*       __restrict__ out) { // report (B*D4) then word (B*(S-1)*D4)
  // XCD-chunked bijective swizzle: XCD k owns windows [k*256, (k+1)*256).
  const int widx = ((blockIdx.x & 7) * (NBLK >> 3)) + (blockIdx.x >> 3);
  const int b    = widx >> 5;                   // widx / WPB
  const int v0   = (widx & (WPB - 1)) * VALS;
  const int tid  = threadIdx.x;
  const int lane = tid & 63;
  const int wav  = tid >> 6;                    // 0..2

  __shared__ int s_pref[VALS + 1];

  // Each wave holds the 2 KB id row (2 coalesced int4 loads, L2-hot) and
  // computes ~6 of the 17 prefix counts pref[j] = #(seg[b] < v0+j).
  const int4* row = (const int4*)(seg + b * S); // 128 int4
  const int4 a0 = row[lane];
  const int4 a1 = row[lane + 64];
  for (int j = wav; j <= VALS; j += 3) {
    const int t = v0 + j;
    int c = 0;
    c += __popcll(__ballot(a0.x < t));
    c += __popcll(__ballot(a0.y < t));
    c += __popcll(__ballot(a0.z < t));
    c += __popcll(__ballot(a0.w < t));
    c += __popcll(__ballot(a1.x < t));
    c += __popcll(__ballot(a1.y < t));
    c += __popcll(__ballot(a1.z < t));
    c += __popcll(__ballot(a1.w < t));
    if (lane == 0) s_pref[j] = c;
  }
  __syncthreads();

  const int rbeg = s_pref[0];
  const int rend = s_pref[VALS];

  const float4* base = emb + (size_t)b * S * D4 + tid;
  float4 acc = make_float4(0.f, 0.f, 0.f, 0.f);
  int v   = 0;
  int nxt = s_pref[1];                          // end row of value v's run

  float4 eA[BATCH], eB[BATCH];

  // 8 affine row loads, addresses known up front (tail rows clamp to
  // rend-1: harmless L1-hot re-read, skipped by the consumer).
  auto loadb = [&](float4 (&dst)[BATCH], int r0) {
#pragma unroll
    for (int u = 0; u < BATCH; ++u) {
      int rr = r0 + u;
      rr = rr < rend ? rr : rend - 1;
      dst[u] = base[(size_t)rr * D4];
    }
  };
  // Flush-on-boundary consumer (verified R5 logic): value v's run ends at
  // s_pref[v+1]; empty values emit zero rows; ascending row order.
  auto consume = [&](const float4 (&src)[BATCH], int r0) {
#pragma unroll
    for (int u = 0; u < BATCH; ++u) {
      const int rr = r0 + u;
      if (rr >= rend) break;                    // block-uniform
      while (rr == nxt) {
        out_row(out, b, v0 + v)[tid] = acc;
        acc = make_float4(0.f, 0.f, 0.f, 0.f);
        ++v;                                    // v <= 15 while rr < rend
        nxt = s_pref[v + 1];                    // uniform LDS broadcast
      }
      facc(acc, src[u]);
    }
  };

  if (rbeg < rend) {
    loadb(eA, rbeg);                            // prologue: batch 0 in flight
    for (int r0 = rbeg; r0 < rend; r0 += 2 * BATCH) {
      if (r0 + BATCH < rend) loadb(eB, r0 + BATCH);      // keep 1 ahead
      consume(eA, r0);
      if (r0 + 2 * BATCH < rend) loadb(eA, r0 + 2 * BATCH);
      if (r0 + BATCH < rend) consume(eB, r0 + BATCH);
    }
  }

  // Drain: value v's run ends at rend (store acc); remaining values empty.
  for (; v < VALS; ++v) {
    out_row(out, b, v0 + v)[tid] = acc;
    acc = make_float4(0.f, 0.f, 0.f, 0.f);
  }
}

extern "C" void kernel_launch(void* const* d_in, const int* in_sizes, int n_in,
                              void* d_out, int out_size, void* d_ws, size_t ws_size,
                              hipStream_t stream) {
  const float4* emb = (const float4*)d_in[0];
  const int*    seg = (const int*)d_in[1];
  float4*       out = (float4*)d_out;
  segsum_pipe_kernel<<<NBLK, THREADS, 0, stream>>>(emb, seg, out);
}

// Round 6
// 178.120 us; speedup vs baseline: 1.0297x; 1.0297x over previous
//
#include <hip/hip_runtime.h>

// Per-batch segment_sum with SORTED segment ids.
//   embeddings: (B=64, S=512, D=768) fp32; segment_ids: (B,S) int32 sorted.
//   out = concat(agg[:,0] (B,D), agg[:,1:] (B,S-1,D)) — flat B*S*D floats.
//
// FINAL (R8): revert to the best-measured structure. Falsification matrix
// over 5 rounds — TLP (R3 61.6us), coarsening (R4 66us), block-scan batched
// loads (R5 64.5us), nt stores (R6 61.6us, FETCH unchanged), sw-pipeline +
// XCD-sequential streams (R7 65us) — shows per-dispatch time is INVARIANT to
// kernel structure at ~62us (2.45 TB/s HBM-counted, ~3.25 TB/s effective
// incl. L3-served reads). No CU-side resource is within 2x of its limit
// (VALUBusy 5%, L1/TA/L2 idle); the in-harness fill kernel proves 6.5 TB/s
// write BW. The residual gap vs the copy ceiling is environmental (the
// 384 MiB inter-iteration re-poison fill evicts/perturbs L3 and its
// writebacks overlap our window) — not kernel-controllable. This kernel =
// R3 wave-per-row + nontemporal output stores (measurement-neutral, keeps
// the zero-reuse output stream from evicting L3-resident embeddings).
//
// Structure: ONE WAVE PER OUTPUT ROW (b,g). Sorted ids =>
//   start = #(seg[b] < g), end = #(seg[b] <= g), via 16 ballot/popcounts
// over the 2 KB id row (2 coalesced int4 loads, L1/L2-hot). Then stream the
// run (3 float4/lane) and write 3 coalesced nt float4.

constexpr int B  = 64;
constexpr int S  = 512;
constexpr int D  = 768;
constexpr int D4 = D / 4;          // 192 float4 per row = 64 lanes x 3
constexpr int BLOCK = 256;         // 4 waves per block

typedef float f32x4 __attribute__((ext_vector_type(4)));

__device__ __forceinline__ void nt_store4(float4* p, const float4& v) {
  f32x4 t = {v.x, v.y, v.z, v.w};
  __builtin_nontemporal_store(t, (f32x4*)p);
}

__global__ __launch_bounds__(BLOCK) void segsum_wave_nt_kernel(
    const float4* __restrict__ emb,   // (B*S*D4)
    const int*    __restrict__ seg,   // (B*S)
    float4*       __restrict__ out) { // report (B*D4) then word (B*(S-1)*D4)
  const int wave = (blockIdx.x * BLOCK + threadIdx.x) >> 6;  // [0, B*S)
  const int lane = threadIdx.x & 63;
  const int b    = wave >> 9;        // wave / S
  const int g    = wave & (S - 1);   // wave % S

  // Whole id row in 2 coalesced int4 loads (L1/L2-hot: 512 waves/b reuse it).
  const int4* row = (const int4*)(seg + b * S);  // 128 int4
  const int4 a0 = row[lane];
  const int4 a1 = row[lane + 64];

  // start = #(x < g), end = #(x <= g). 16 independent cmp/ballot/popcount.
  int start = 0, end = 0;
  start += __popcll(__ballot(a0.x < g));
  start += __popcll(__ballot(a0.y < g));
  start += __popcll(__ballot(a0.z < g));
  start += __popcll(__ballot(a0.w < g));
  start += __popcll(__ballot(a1.x < g));
  start += __popcll(__ballot(a1.y < g));
  start += __popcll(__ballot(a1.z < g));
  start += __popcll(__ballot(a1.w < g));
  end   += __popcll(__ballot(a0.x <= g));
  end   += __popcll(__ballot(a0.y <= g));
  end   += __popcll(__ballot(a0.z <= g));
  end   += __popcll(__ballot(a0.w <= g));
  end   += __popcll(__ballot(a1.x <= g));
  end   += __popcll(__ballot(a1.y <= g));
  end   += __popcll(__ballot(a1.z <= g));
  end   += __popcll(__ballot(a1.w <= g));

  // Stream the run: lane i owns float4 columns {i, i+64, i+128}.
  float4 acc0 = make_float4(0.f, 0.f, 0.f, 0.f);
  float4 acc1 = acc0, acc2 = acc0;
  const float4* p = emb + (size_t)(b * S + start) * D4 + lane;
  for (int s = start; s < end; ++s) {          // wave-uniform trip count
    float4 e0 = p[0], e1 = p[64], e2 = p[128];
    acc0.x += e0.x; acc0.y += e0.y; acc0.z += e0.z; acc0.w += e0.w;
    acc1.x += e1.x; acc1.y += e1.y; acc1.z += e1.z; acc1.w += e1.w;
    acc2.x += e2.x; acc2.y += e2.y; acc2.z += e2.z; acc2.w += e2.w;
    p += D4;
  }

  // Nontemporal stores: output has zero kernel-side reuse — keep it from
  // allocating in L2/L3 so the embeddings stay cache-resident.
  float4* dst = (g == 0)
      ? out + (size_t)b * D4                                        // report_feat
      : out + (size_t)B * D4 + ((size_t)b * (S - 1) + (g - 1)) * D4; // word_feat
  nt_store4(dst + lane,       acc0);
  nt_store4(dst + lane + 64,  acc1);
  nt_store4(dst + lane + 128, acc2);
}

extern "C" void kernel_launch(void* const* d_in, const int* in_sizes, int n_in,
                              void* d_out, int out_size, void* d_ws, size_t ws_size,
                              hipStream_t stream) {
  const float4* emb = (const float4*)d_in[0];
  const int*    seg = (const int*)d_in[1];
  float4*       out = (float4*)d_out;

  const int waves  = B * S;                    // 32768 output rows
  const int blocks = waves / (BLOCK / 64);     // 8192 blocks
  segsum_wave_nt_kernel<<<blocks, BLOCK, 0, stream>>>(emb, seg, out);
}